// Round 1
// baseline (311.515 us; speedup 1.0000x reference)
//
#include <hip/hip_runtime.h>
#include <hip/hip_bf16.h>

#define B_ 2
#define C_ 256
#define N_ 4096
#define NH_ 8
#define HD_ 32
#define SCALE_ 0.17677669529663687f

typedef __attribute__((ext_vector_type(8))) short bf16x8;
typedef __attribute__((ext_vector_type(4))) float f32x4;

__device__ inline short f2b(float f) {
    __hip_bfloat16 h = __float2bfloat16(f);
    return __builtin_bit_cast(short, h);
}

// ---------------------------------------------------------------------------
// proj_cmajor: Out[do][n] = sum_c W[do][c] * In[b][c][n] + bias[do]
//   In: fp32 [B][256][N] (channel-major, n contiguous)
//   W : fp32 [DO][256] row-major
//   d < 256  -> outA bf16 [b][h=d/32][n][d%32]   (Q/K head layout), val*scaleA
//   d >= 256 -> outV bf16 [b][d-256][n]          (V natural layout)
// Grid: (N/64, DO/256, B), 256 threads (4 waves), wave owns 64 do-rows.
// ---------------------------------------------------------------------------
__global__ __launch_bounds__(256) void proj_cmajor(
    const float* __restrict__ In, const float* __restrict__ W,
    const float* __restrict__ bias, short* __restrict__ outA,
    short* __restrict__ outV, float scaleA)
{
    const int b  = blockIdx.z;
    const int do0 = blockIdx.y * 256;
    const int n0 = blockIdx.x * 64;
    const int tid = threadIdx.x;
    const int w = tid >> 6, l = tid & 63, lg = l >> 4, lr = l & 15;

    __shared__ short lds[64][40];  // [n][c] bf16, padded stride 40

    f32x4 acc[4][4] = {};  // [doblk][nblk]
    const float* Inb = In + (size_t)b * C_ * N_;

    for (int c0 = 0; c0 < C_; c0 += 32) {
        __syncthreads();
        {
            const int cc = tid >> 3;          // 0..31 channel row
            const int nn = (tid & 7) * 8;     // 0..56 col base
            const float* src = Inb + (size_t)(c0 + cc) * N_ + n0 + nn;
            float4 f0 = *(const float4*)src;
            float4 f1 = *(const float4*)(src + 4);
            lds[nn + 0][cc] = f2b(f0.x); lds[nn + 1][cc] = f2b(f0.y);
            lds[nn + 2][cc] = f2b(f0.z); lds[nn + 3][cc] = f2b(f0.w);
            lds[nn + 4][cc] = f2b(f1.x); lds[nn + 5][cc] = f2b(f1.y);
            lds[nn + 6][cc] = f2b(f1.z); lds[nn + 7][cc] = f2b(f1.w);
        }
        __syncthreads();

        bf16x8 af[4];
        #pragma unroll
        for (int db = 0; db < 4; db++) {
            const float* wp = W + (size_t)(do0 + w * 64 + db * 16 + lr) * C_ + c0 + lg * 8;
            float t[8];
            *(float4*)t       = *(const float4*)wp;
            *(float4*)(t + 4) = *(const float4*)(wp + 4);
            #pragma unroll
            for (int i = 0; i < 8; i++) af[db][i] = f2b(t[i]);
        }
        #pragma unroll
        for (int nb = 0; nb < 4; nb++) {
            bf16x8 bfr = *(const bf16x8*)&lds[nb * 16 + lr][lg * 8];
            #pragma unroll
            for (int db = 0; db < 4; db++)
                acc[db][nb] = __builtin_amdgcn_mfma_f32_16x16x32_bf16(
                    af[db], bfr, acc[db][nb], 0, 0, 0);
        }
    }

    #pragma unroll
    for (int db = 0; db < 4; db++) {
        #pragma unroll
        for (int r = 0; r < 4; r++) {
            const int d = do0 + w * 64 + db * 16 + lg * 4 + r;
            const float bs = bias[d];
            #pragma unroll
            for (int nb = 0; nb < 4; nb++) {
                const int n = n0 + nb * 16 + lr;
                float v = acc[db][nb][r] + bs;
                if (d < 256) {
                    outA[(((size_t)(b * NH_ + (d >> 5)) * N_) + n) * HD_ + (d & 31)]
                        = f2b(v * scaleA);
                } else {
                    outV[((size_t)(b * C_) + (d - 256)) * N_ + n] = f2b(v);
                }
            }
        }
    }
}

// ---------------------------------------------------------------------------
// attn_kernel: flash attention, one block = (b, h, 64 q-rows), 4 waves x 16 q.
//   Q,K: bf16 [b][h][n][32] (SCALE pre-folded into Q), V: bf16 [b][h][d][n]
//   AO : bf16 [b][n][256]
// ---------------------------------------------------------------------------
__global__ __launch_bounds__(256) void attn_kernel(
    const short* __restrict__ Qb, const short* __restrict__ Kb,
    const short* __restrict__ Vb, short* __restrict__ AO)
{
    const int b = blockIdx.z, h = blockIdx.y;
    const int tid = threadIdx.x, w = tid >> 6, l = tid & 63, lg = l >> 4, lr = l & 15;
    const int q0 = blockIdx.x * 64 + w * 16;

    const short* Qp = Qb + ((size_t)(b * NH_ + h) * N_) * HD_;
    const short* Kp = Kb + ((size_t)(b * NH_ + h) * N_) * HD_;
    const short* Vp = Vb + ((size_t)(b * NH_ + h) * HD_) * N_;

    __shared__ short p_lds[4][16][40];  // per-wave [q][m] bf16, padded

    bf16x8 qf = *(const bf16x8*)&Qp[(size_t)(q0 + lr) * HD_ + lg * 8];

    f32x4 acc0 = {}, acc1 = {};
    float mrow[4], lsum[4];
    #pragma unroll
    for (int r = 0; r < 4; r++) { mrow[r] = -1e30f; lsum[r] = 0.0f; }

    for (int m0 = 0; m0 < N_; m0 += 32) {
        bf16x8 kf0 = *(const bf16x8*)&Kp[(size_t)(m0 + lr) * HD_ + lg * 8];
        bf16x8 kf1 = *(const bf16x8*)&Kp[(size_t)(m0 + 16 + lr) * HD_ + lg * 8];
        f32x4 z = {};
        f32x4 s0 = __builtin_amdgcn_mfma_f32_16x16x32_bf16(qf, kf0, z, 0, 0, 0);
        f32x4 s1 = __builtin_amdgcn_mfma_f32_16x16x32_bf16(qf, kf1, z, 0, 0, 0);

        // row-max over the 16 m-columns (lanes lr within each 16-lane group)
        float tm[4];
        #pragma unroll
        for (int r = 0; r < 4; r++) tm[r] = fmaxf(s0[r], s1[r]);
        #pragma unroll
        for (int off = 1; off < 16; off <<= 1) {
            #pragma unroll
            for (int r = 0; r < 4; r++) tm[r] = fmaxf(tm[r], __shfl_xor(tm[r], off));
        }

        float rs[4];
        #pragma unroll
        for (int r = 0; r < 4; r++) {
            float mn = fmaxf(mrow[r], tm[r]);
            float sc = __expf(mrow[r] - mn);
            mrow[r] = mn;
            lsum[r] *= sc;
            acc0[r] *= sc; acc1[r] *= sc;
            float p0 = __expf(s0[r] - mn);
            float p1 = __expf(s1[r] - mn);
            rs[r] = p0 + p1;
            p_lds[w][lg * 4 + r][lr]      = f2b(p0);
            p_lds[w][lg * 4 + r][16 + lr] = f2b(p1);
        }
        #pragma unroll
        for (int off = 1; off < 16; off <<= 1) {
            #pragma unroll
            for (int r = 0; r < 4; r++) rs[r] += __shfl_xor(rs[r], off);
        }
        #pragma unroll
        for (int r = 0; r < 4; r++) lsum[r] += rs[r];

        // P as A-fragment (intra-wave LDS roundtrip; compiler inserts lgkmcnt)
        bf16x8 pf  = *(const bf16x8*)&p_lds[w][lr][lg * 8];
        bf16x8 vf0 = *(const bf16x8*)&Vp[(size_t)lr * N_ + m0 + lg * 8];
        bf16x8 vf1 = *(const bf16x8*)&Vp[(size_t)(16 + lr) * N_ + m0 + lg * 8];
        acc0 = __builtin_amdgcn_mfma_f32_16x16x32_bf16(pf, vf0, acc0, 0, 0, 0);
        acc1 = __builtin_amdgcn_mfma_f32_16x16x32_bf16(pf, vf1, acc1, 0, 0, 0);
    }

    #pragma unroll
    for (int r = 0; r < 4; r++) {
        const int n = q0 + lg * 4 + r;
        const float inv = 1.0f / lsum[r];
        AO[((size_t)b * N_ + n) * C_ + h * HD_ + lr]      = f2b(acc0[r] * inv);
        AO[((size_t)b * N_ + n) * C_ + h * HD_ + 16 + lr] = f2b(acc1[r] * inv);
    }
}

// ---------------------------------------------------------------------------
// proj_out: Out[b][d][n] = sum_c Wo[d][c] * AO[b][n][c] + bo[d]  (fp32 out)
// Grid: (N/64, 1, B), 256 threads, wave owns 64 d-rows.
// ---------------------------------------------------------------------------
__global__ __launch_bounds__(256) void proj_out(
    const short* __restrict__ AO, const float* __restrict__ W,
    const float* __restrict__ bias, float* __restrict__ Out)
{
    const int b = blockIdx.z;
    const int n0 = blockIdx.x * 64;
    const int tid = threadIdx.x, w = tid >> 6, l = tid & 63, lg = l >> 4, lr = l & 15;

    f32x4 acc[4][4] = {};

    for (int c0 = 0; c0 < C_; c0 += 32) {
        bf16x8 af[4];
        #pragma unroll
        for (int db = 0; db < 4; db++) {
            const float* wp = W + (size_t)(w * 64 + db * 16 + lr) * C_ + c0 + lg * 8;
            float t[8];
            *(float4*)t       = *(const float4*)wp;
            *(float4*)(t + 4) = *(const float4*)(wp + 4);
            #pragma unroll
            for (int i = 0; i < 8; i++) af[db][i] = f2b(t[i]);
        }
        #pragma unroll
        for (int nb = 0; nb < 4; nb++) {
            bf16x8 bfr = *(const bf16x8*)&AO[((size_t)b * N_ + n0 + nb * 16 + lr) * C_ + c0 + lg * 8];
            #pragma unroll
            for (int db = 0; db < 4; db++)
                acc[db][nb] = __builtin_amdgcn_mfma_f32_16x16x32_bf16(
                    af[db], bfr, acc[db][nb], 0, 0, 0);
        }
    }

    #pragma unroll
    for (int db = 0; db < 4; db++) {
        #pragma unroll
        for (int r = 0; r < 4; r++) {
            const int d = w * 64 + db * 16 + lg * 4 + r;
            const float bs = bias[d];
            #pragma unroll
            for (int nb = 0; nb < 4; nb++) {
                const int n = n0 + nb * 16 + lr;
                Out[((size_t)(b * C_) + d) * N_ + n] = acc[db][nb][r] + bs;
            }
        }
    }
}

// ---------------------------------------------------------------------------
extern "C" void kernel_launch(void* const* d_in, const int* in_sizes, int n_in,
                              void* d_out, int out_size, void* d_ws, size_t ws_size,
                              hipStream_t stream) {
    const float* dec = (const float*)d_in[0];
    const float* enc = (const float*)d_in[1];
    const float* Wq  = (const float*)d_in[2];
    const float* bq  = (const float*)d_in[3];
    const float* Wkv = (const float*)d_in[4];
    const float* bkv = (const float*)d_in[5];
    const float* Wo  = (const float*)d_in[6];
    const float* bo  = (const float*)d_in[7];
    float* out = (float*)d_out;

    // workspace: Q, K: [B][8][N][32] bf16; V: [B][256][N] bf16; AO: [B][N][256] bf16
    const size_t SEG = (size_t)B_ * NH_ * N_ * HD_;  // 2,097,152 elements
    short* Qb  = (short*)d_ws;
    short* Kb  = Qb + SEG;
    short* Vb  = Kb + SEG;
    short* AOb = Vb + SEG;   // total 16 MB

    // Q projection (SCALE folded into Q)
    proj_cmajor<<<dim3(N_ / 64, 1, B_), 256, 0, stream>>>(dec, Wq, bq, Qb, nullptr, SCALE_);
    // KV projection (K to head layout, V to [d][n] layout)
    proj_cmajor<<<dim3(N_ / 64, 2, B_), 256, 0, stream>>>(enc, Wkv, bkv, Kb, Vb, 1.0f);
    // flash attention
    attn_kernel<<<dim3(N_ / 64, NH_, B_), 256, 0, stream>>>(Qb, Kb, Vb, AOb);
    // output projection
    proj_out<<<dim3(N_ / 64, 1, B_), 256, 0, stream>>>(AOb, Wo, bo, out);
}

// Round 2
// 249.728 us; speedup vs baseline: 1.2474x; 1.2474x over previous
//
#include <hip/hip_runtime.h>
#include <hip/hip_bf16.h>

#define B_ 2
#define C_ 256
#define N_ 4096
#define NH_ 8
#define HD_ 32
#define SCALE_ 0.17677669529663687f
#define LOG2E_ 1.4426950408889634f

typedef __attribute__((ext_vector_type(8))) short bf16x8;
typedef __attribute__((ext_vector_type(4))) float f32x4;

__device__ inline short f2b(float f) {
    __hip_bfloat16 h = __float2bfloat16(f);
    return __builtin_bit_cast(short, h);
}

// pack two f32 -> one dword of 2 bf16 (lo = a, hi = b), RNE
__device__ inline unsigned pk2(float a, float b) {
    unsigned r;
    asm("v_cvt_pk_bf16_f32 %0, %1, %2" : "=v"(r) : "v"(a), "v"(b));
    return r;
}

// ---------------------------------------------------------------------------
// proj_cmajor: Out[do][n] = sum_c W[do][c] * In[b][c][n] + bias[do]
//   d < 256  -> outA bf16 [b][h=d/32][n][d%32]   (Q/K head layout), val*scaleA
//   d >= 256 -> outV bf16 [b][d-256][n]          (V natural layout)
// ---------------------------------------------------------------------------
__global__ __launch_bounds__(256) void proj_cmajor(
    const float* __restrict__ In, const float* __restrict__ W,
    const float* __restrict__ bias, short* __restrict__ outA,
    short* __restrict__ outV, float scaleA)
{
    const int b  = blockIdx.z;
    const int do0 = blockIdx.y * 256;
    const int n0 = blockIdx.x * 64;
    const int tid = threadIdx.x;
    const int w = tid >> 6, l = tid & 63, lg = l >> 4, lr = l & 15;

    __shared__ short lds[64][40];  // [n][c] bf16, padded stride 40

    f32x4 acc[4][4] = {};  // [doblk][nblk]
    const float* Inb = In + (size_t)b * C_ * N_;

    for (int c0 = 0; c0 < C_; c0 += 32) {
        __syncthreads();
        {
            const int cc = tid >> 3;          // 0..31 channel row
            const int nn = (tid & 7) * 8;     // 0..56 col base
            const float* src = Inb + (size_t)(c0 + cc) * N_ + n0 + nn;
            float4 f0 = *(const float4*)src;
            float4 f1 = *(const float4*)(src + 4);
            lds[nn + 0][cc] = f2b(f0.x); lds[nn + 1][cc] = f2b(f0.y);
            lds[nn + 2][cc] = f2b(f0.z); lds[nn + 3][cc] = f2b(f0.w);
            lds[nn + 4][cc] = f2b(f1.x); lds[nn + 5][cc] = f2b(f1.y);
            lds[nn + 6][cc] = f2b(f1.z); lds[nn + 7][cc] = f2b(f1.w);
        }
        __syncthreads();

        bf16x8 af[4];
        #pragma unroll
        for (int db = 0; db < 4; db++) {
            const float* wp = W + (size_t)(do0 + w * 64 + db * 16 + lr) * C_ + c0 + lg * 8;
            float t[8];
            *(float4*)t       = *(const float4*)wp;
            *(float4*)(t + 4) = *(const float4*)(wp + 4);
            #pragma unroll
            for (int i = 0; i < 8; i++) af[db][i] = f2b(t[i]);
        }
        #pragma unroll
        for (int nb = 0; nb < 4; nb++) {
            bf16x8 bfr = *(const bf16x8*)&lds[nb * 16 + lr][lg * 8];
            #pragma unroll
            for (int db = 0; db < 4; db++)
                acc[db][nb] = __builtin_amdgcn_mfma_f32_16x16x32_bf16(
                    af[db], bfr, acc[db][nb], 0, 0, 0);
        }
    }

    #pragma unroll
    for (int db = 0; db < 4; db++) {
        #pragma unroll
        for (int r = 0; r < 4; r++) {
            const int d = do0 + w * 64 + db * 16 + lg * 4 + r;
            const float bs = bias[d];
            #pragma unroll
            for (int nb = 0; nb < 4; nb++) {
                const int n = n0 + nb * 16 + lr;
                float v = acc[db][nb][r] + bs;
                if (d < 256) {
                    outA[(((size_t)(b * NH_ + (d >> 5)) * N_) + n) * HD_ + (d & 31)]
                        = f2b(v * scaleA);
                } else {
                    outV[((size_t)(b * C_) + (d - 256)) * N_ + n] = f2b(v);
                }
            }
        }
    }
}

// ---------------------------------------------------------------------------
// attn_kernel: flash attention, swapped-QK^T form.
//   S^T = mfma(A=K, B=Q): lane owns ONE q-row (col lr), k = 16t + 4lg + r.
//   Q has SCALE*log2e pre-folded, so softmax uses raw exp2.
//   PV: out^T = mfma(A=V^T, B=P^T), P^T routed through packed LDS (b64 w / b128 r).
//   Q,K: bf16 [b][h][n][32], V: bf16 [b][h][d][n], AO: bf16 [b][n][256]
// ---------------------------------------------------------------------------
__global__ __launch_bounds__(256) void attn_kernel(
    const short* __restrict__ Qb, const short* __restrict__ Kb,
    const short* __restrict__ Vb, short* __restrict__ AO)
{
    // XCD-aware bijective swizzle: 1024 blocks -> 128 consecutive per XCD
    // (2 full (b,h) K/V sets per XCD -> ~1MB L2 working set, resident)
    const int lin = blockIdx.x + 64 * (blockIdx.y + 8 * blockIdx.z);
    const int wg  = (lin & 7) * 128 + (lin >> 3);
    const int qt = wg & 63, h = (wg >> 6) & 7, b = wg >> 9;

    const int tid = threadIdx.x, w = tid >> 6, l = tid & 63;
    const int lg = l >> 4, lr = l & 15;
    const int q0 = qt * 64 + w * 16;

    const short* Qp = Qb + ((size_t)(b * NH_ + h) * N_) * HD_;
    const short* Kp = Kb + ((size_t)(b * NH_ + h) * N_) * HD_;
    const short* Vp = Vb + ((size_t)(b * NH_ + h) * HD_) * N_;

    __shared__ short pbuf[4][16][72];  // per-wave [q][k] bf16, 144B rows

    bf16x8 qf = *(const bf16x8*)&Qp[(size_t)(q0 + lr) * HD_ + lg * 8];

    f32x4 acc0 = {}, acc1 = {};     // out^T: d = 4lg+r (+16), q = lr
    float mrow = -1e30f, lsum = 0.0f;

    for (int m0 = 0; m0 < N_; m0 += 64) {
        f32x4 z = {};
        f32x4 s[4];
        #pragma unroll
        for (int t = 0; t < 4; t++) {
            bf16x8 kf = *(const bf16x8*)&Kp[(size_t)(m0 + 16 * t + lr) * HD_ + lg * 8];
            s[t] = __builtin_amdgcn_mfma_f32_16x16x32_bf16(kf, qf, z, 0, 0, 0);
        }
        // V loads issued early; latency hides under softmax
        bf16x8 vf[2][2];
        #pragma unroll
        for (int c = 0; c < 2; c++) {
            vf[c][0] = *(const bf16x8*)&Vp[(size_t)lr * N_ + m0 + 32 * c + 8 * lg];
            vf[c][1] = *(const bf16x8*)&Vp[(size_t)(16 + lr) * N_ + m0 + 32 * c + 8 * lg];
        }

        // row max: 15 in-reg + 2 shuffles (k spans regs + lg only)
        float tm = s[0][0];
        #pragma unroll
        for (int t = 0; t < 4; t++)
            #pragma unroll
            for (int r = 0; r < 4; r++) tm = fmaxf(tm, s[t][r]);
        tm = fmaxf(tm, __shfl_xor(tm, 16));
        tm = fmaxf(tm, __shfl_xor(tm, 32));

        // rescale only when some row's max grew (exact: skipped => all p <= 1)
        if (__any(tm > mrow)) {
            float mn = fmaxf(mrow, tm);
            float sc = __builtin_amdgcn_exp2f(mrow - mn);
            mrow = mn;
            lsum *= sc;
            #pragma unroll
            for (int r = 0; r < 4; r++) { acc0[r] *= sc; acc1[r] *= sc; }
        }

        float p[4][4];
        float rs = 0.0f;
        #pragma unroll
        for (int t = 0; t < 4; t++)
            #pragma unroll
            for (int r = 0; r < 4; r++) {
                p[t][r] = __builtin_amdgcn_exp2f(s[t][r] - mrow);
                rs += p[t][r];
            }
        rs += __shfl_xor(rs, 16);
        rs += __shfl_xor(rs, 32);
        lsum += rs;

        // pack P -> bf16 pairs, one b64 LDS write per t (k-local = 16t+4lg+{0..3})
        #pragma unroll
        for (int t = 0; t < 4; t++) {
            uint2 d;
            d.x = pk2(p[t][0], p[t][1]);
            d.y = pk2(p[t][2], p[t][3]);
            *(uint2*)&pbuf[w][lr][16 * t + 4 * lg] = d;
        }

        // P^T as B-frag: lane reads [q=lr][k = 32c + 8lg + j]
        #pragma unroll
        for (int c = 0; c < 2; c++) {
            bf16x8 pf = *(const bf16x8*)&pbuf[w][lr][32 * c + 8 * lg];
            acc0 = __builtin_amdgcn_mfma_f32_16x16x32_bf16(vf[c][0], pf, acc0, 0, 0, 0);
            acc1 = __builtin_amdgcn_mfma_f32_16x16x32_bf16(vf[c][1], pf, acc1, 0, 0, 0);
        }
    }

    const float inv = 1.0f / lsum;
    uint2 o;
    o.x = pk2(acc0[0] * inv, acc0[1] * inv);
    o.y = pk2(acc0[2] * inv, acc0[3] * inv);
    *(uint2*)&AO[((size_t)b * N_ + q0 + lr) * C_ + h * HD_ + 4 * lg] = o;
    o.x = pk2(acc1[0] * inv, acc1[1] * inv);
    o.y = pk2(acc1[2] * inv, acc1[3] * inv);
    *(uint2*)&AO[((size_t)b * N_ + q0 + lr) * C_ + h * HD_ + 16 + 4 * lg] = o;
}

// ---------------------------------------------------------------------------
// proj_out: Out[b][d][n] = sum_c Wo[d][c] * AO[b][n][c] + bo[d]  (fp32 out)
// ---------------------------------------------------------------------------
__global__ __launch_bounds__(256) void proj_out(
    const short* __restrict__ AO, const float* __restrict__ W,
    const float* __restrict__ bias, float* __restrict__ Out)
{
    const int b = blockIdx.z;
    const int n0 = blockIdx.x * 64;
    const int tid = threadIdx.x, w = tid >> 6, l = tid & 63, lg = l >> 4, lr = l & 15;

    f32x4 acc[4][4] = {};

    for (int c0 = 0; c0 < C_; c0 += 32) {
        bf16x8 af[4];
        #pragma unroll
        for (int db = 0; db < 4; db++) {
            const float* wp = W + (size_t)(w * 64 + db * 16 + lr) * C_ + c0 + lg * 8;
            float t[8];
            *(float4*)t       = *(const float4*)wp;
            *(float4*)(t + 4) = *(const float4*)(wp + 4);
            #pragma unroll
            for (int i = 0; i < 8; i++) af[db][i] = f2b(t[i]);
        }
        #pragma unroll
        for (int nb = 0; nb < 4; nb++) {
            bf16x8 bfr = *(const bf16x8*)&AO[((size_t)b * N_ + n0 + nb * 16 + lr) * C_ + c0 + lg * 8];
            #pragma unroll
            for (int db = 0; db < 4; db++)
                acc[db][nb] = __builtin_amdgcn_mfma_f32_16x16x32_bf16(
                    af[db], bfr, acc[db][nb], 0, 0, 0);
        }
    }

    #pragma unroll
    for (int db = 0; db < 4; db++) {
        #pragma unroll
        for (int r = 0; r < 4; r++) {
            const int d = w * 64 + db * 16 + lg * 4 + r;
            const float bs = bias[d];
            #pragma unroll
            for (int nb = 0; nb < 4; nb++) {
                const int n = n0 + nb * 16 + lr;
                Out[((size_t)(b * C_) + d) * N_ + n] = acc[db][nb][r] + bs;
            }
        }
    }
}

// ---------------------------------------------------------------------------
extern "C" void kernel_launch(void* const* d_in, const int* in_sizes, int n_in,
                              void* d_out, int out_size, void* d_ws, size_t ws_size,
                              hipStream_t stream) {
    const float* dec = (const float*)d_in[0];
    const float* enc = (const float*)d_in[1];
    const float* Wq  = (const float*)d_in[2];
    const float* bq  = (const float*)d_in[3];
    const float* Wkv = (const float*)d_in[4];
    const float* bkv = (const float*)d_in[5];
    const float* Wo  = (const float*)d_in[6];
    const float* bo  = (const float*)d_in[7];
    float* out = (float*)d_out;

    const size_t SEG = (size_t)B_ * NH_ * N_ * HD_;  // 2,097,152 elements
    short* Qb  = (short*)d_ws;
    short* Kb  = Qb + SEG;
    short* Vb  = Kb + SEG;
    short* AOb = Vb + SEG;   // total 16 MB

    // Q projection: SCALE * log2e folded in (softmax then uses raw exp2)
    proj_cmajor<<<dim3(N_ / 64, 1, B_), 256, 0, stream>>>(dec, Wq, bq, Qb, nullptr,
                                                          SCALE_ * LOG2E_);
    proj_cmajor<<<dim3(N_ / 64, 2, B_), 256, 0, stream>>>(enc, Wkv, bkv, Kb, Vb, 1.0f);
    attn_kernel<<<dim3(N_ / 64, NH_, B_), 256, 0, stream>>>(Qb, Kb, Vb, AOb);
    proj_out<<<dim3(N_ / 64, 1, B_), 256, 0, stream>>>(AOb, Wo, bo, out);
}

// Round 3
// 135.071 us; speedup vs baseline: 2.3063x; 1.8489x over previous
//
#include <hip/hip_runtime.h>
#include <hip/hip_bf16.h>

#define B_ 2
#define C_ 256
#define N_ 4096
#define NH_ 8
#define HD_ 32
#define KBLK_ 64
#define SCALE_ 0.17677669529663687f
#define LOG2E_ 1.4426950408889634f

typedef __attribute__((ext_vector_type(8))) short bf16x8;
typedef __attribute__((ext_vector_type(4))) float f32x4;

__device__ inline short f2b(float f) {
    __hip_bfloat16 h = __float2bfloat16(f);
    return __builtin_bit_cast(short, h);
}

__device__ inline unsigned pk2(float a, float b) {
    unsigned r;
    asm("v_cvt_pk_bf16_f32 %0, %1, %2" : "=v"(r) : "v"(a), "v"(b));
    return r;
}

// ---------------------------------------------------------------------------
// proj_qkv: fused Q/K/V projections.
//   grid (N/64, 6, B): y<2 -> Q rows y*128 (dec, scale folded); y=2,3 -> K rows;
//   y=4,5 -> V rows. Block = 128 do x 64 n, 4 waves (wave = 64 do x 32 n).
// ---------------------------------------------------------------------------
__global__ __launch_bounds__(256) void proj_qkv(
    const float* __restrict__ dec, const float* __restrict__ enc,
    const float* __restrict__ Wq, const float* __restrict__ bq,
    const float* __restrict__ Wkv, const float* __restrict__ bkv,
    short* __restrict__ Qb, short* __restrict__ Kb, short* __restrict__ Vb)
{
    const int b = blockIdx.z, y = blockIdx.y;
    const int n0 = blockIdx.x * 64;
    const bool isQ = (y < 2);
    const float* In   = isQ ? dec : enc;
    const float* W    = isQ ? Wq : Wkv;
    const float* bias = isQ ? bq : bkv;
    const int row0 = isQ ? y * 128 : (y - 2) * 128;

    const int tid = threadIdx.x;
    const int w = tid >> 6, l = tid & 63, lg = l >> 4, lr = l & 15;
    const int w2 = w >> 1, w1 = w & 1;   // do-half, n-half

    __shared__ short lds[64][40];  // [n][c] bf16, padded

    f32x4 acc[4][2] = {};
    const float* Inb = In + (size_t)b * C_ * N_;

    for (int c0 = 0; c0 < C_; c0 += 32) {
        __syncthreads();
        {
            const int cc = tid >> 3;
            const int nn = (tid & 7) * 8;
            const float* src = Inb + (size_t)(c0 + cc) * N_ + n0 + nn;
            float4 f0 = *(const float4*)src;
            float4 f1 = *(const float4*)(src + 4);
            lds[nn + 0][cc] = f2b(f0.x); lds[nn + 1][cc] = f2b(f0.y);
            lds[nn + 2][cc] = f2b(f0.z); lds[nn + 3][cc] = f2b(f0.w);
            lds[nn + 4][cc] = f2b(f1.x); lds[nn + 5][cc] = f2b(f1.y);
            lds[nn + 6][cc] = f2b(f1.z); lds[nn + 7][cc] = f2b(f1.w);
        }
        __syncthreads();

        bf16x8 af[4];
        #pragma unroll
        for (int db = 0; db < 4; db++) {
            const float* wp = W + (size_t)(row0 + w2 * 64 + db * 16 + lr) * C_ + c0 + lg * 8;
            float t[8];
            *(float4*)t       = *(const float4*)wp;
            *(float4*)(t + 4) = *(const float4*)(wp + 4);
            #pragma unroll
            for (int i = 0; i < 8; i++) af[db][i] = f2b(t[i]);
        }
        #pragma unroll
        for (int nb = 0; nb < 2; nb++) {
            bf16x8 bfr = *(const bf16x8*)&lds[w1 * 32 + nb * 16 + lr][lg * 8];
            #pragma unroll
            for (int db = 0; db < 4; db++)
                acc[db][nb] = __builtin_amdgcn_mfma_f32_16x16x32_bf16(
                    af[db], bfr, acc[db][nb], 0, 0, 0);
        }
    }

    #pragma unroll
    for (int db = 0; db < 4; db++) {
        #pragma unroll
        for (int r = 0; r < 4; r++) {
            const int dl = row0 + w2 * 64 + db * 16 + lg * 4 + r;
            const float bs = bias[dl];
            #pragma unroll
            for (int nb = 0; nb < 2; nb++) {
                const int n = n0 + w1 * 32 + nb * 16 + lr;
                float v = acc[db][nb][r] + bs;
                if (y < 2) {
                    Qb[(((size_t)(b * NH_ + (dl >> 5)) * N_) + n) * HD_ + (dl & 31)]
                        = f2b(v * (SCALE_ * LOG2E_));
                } else if (y < 4) {
                    Kb[(((size_t)(b * NH_ + (dl >> 5)) * N_) + n) * HD_ + (dl & 31)]
                        = f2b(v);
                } else {
                    Vb[((size_t)(b * C_) + (dl - 256)) * N_ + n] = f2b(v);
                }
            }
        }
    }
}

// ---------------------------------------------------------------------------
// attn_kernel: flash attention, 8 waves x 16 q = 128 q per block.
//   K/V staged in double-buffered LDS shared by all waves (global traffic /8).
//   2-phase pipeline: prefetch tile t+1 to regs, consume tile t, ds_write, barrier.
//   Swapped QK^T (S^T = mfma(K,Q)); P routed through XOR-swizzled pbuf.
// ---------------------------------------------------------------------------
__global__ __launch_bounds__(512) void attn_kernel(
    const short* __restrict__ Qb, const short* __restrict__ Kb,
    const short* __restrict__ Vb, short* __restrict__ AO)
{
    // XCD swizzle: 512 blocks = 8 XCDs x 64; 64 consecutive wg = 2 heads (~2MB L2)
    const int lin = blockIdx.x + 32 * (blockIdx.y + 8 * blockIdx.z);
    const int wg  = (lin & 7) * 64 + (lin >> 3);
    const int qblk = wg & 31, h = (wg >> 5) & 7, b = wg >> 8;

    const int tid = threadIdx.x, w = tid >> 6, l = tid & 63;
    const int lg = l >> 4, lr = l & 15;
    const int q0 = qblk * 128 + w * 16;

    const short* Qp = Qb + ((size_t)(b * NH_ + h) * N_) * HD_;
    const short* Kp = Kb + ((size_t)(b * NH_ + h) * N_) * HD_;
    const short* Vp = Vb + ((size_t)(b * NH_ + h) * HD_) * N_;

    __shared__ short Kt[2][KBLK_][HD_];   // [key][hd] bf16, naturally phase-balanced
    __shared__ short Vt[2][HD_][KBLK_];   // [d][key] bf16, 16B-slot XOR (slot^(d&7))
    __shared__ short pbuf[8][16][72];     // per-wave P, short-offset ^ (lr&8)

    // staging roles: threads 0-255 stage K (4KB), 256-511 stage V (4KB)
    const int sh = tid >> 8;       // 0 = K, 1 = V (wave-uniform)
    const int su = tid & 255;
    const int kkey = su >> 2, kslot = su & 3;           // K: 4 x 16B per key row
    const int vd = su >> 3, vslot = su & 7;             // V: 8 x 16B per d row
    const int vphys = (vslot ^ (vd & 7)) * 8;           // swizzled short offset

    bf16x8 qf = *(const bf16x8*)&Qp[(size_t)(q0 + lr) * HD_ + lg * 8];

    f32x4 acc0 = {}, acc1 = {};
    float mrow = -1e30f, lsum = 0.0f;

    // prologue: stage tile 0
    {
        uint4 pr = (sh == 0)
            ? *(const uint4*)(Kp + (size_t)kkey * HD_ + kslot * 8)
            : *(const uint4*)(Vp + (size_t)vd * N_ + vslot * 8);
        if (sh == 0) *(uint4*)&Kt[0][kkey][kslot * 8] = pr;
        else         *(uint4*)&Vt[0][vd][vphys]       = pr;
    }
    __syncthreads();

    for (int it = 0; it < N_ / KBLK_; ++it) {
        const int cur = it & 1;
        const int mnext = (it + 1) * KBLK_;
        uint4 pr;
        if (it + 1 < N_ / KBLK_) {
            pr = (sh == 0)
                ? *(const uint4*)(Kp + (size_t)(mnext + kkey) * HD_ + kslot * 8)
                : *(const uint4*)(Vp + (size_t)vd * N_ + mnext + vslot * 8);
        }

        // ---- consume tile [cur] ----
        f32x4 z = {};
        f32x4 s[4];
        #pragma unroll
        for (int t = 0; t < 4; t++) {
            bf16x8 kf = *(const bf16x8*)&Kt[cur][16 * t + lr][lg * 8];
            s[t] = __builtin_amdgcn_mfma_f32_16x16x32_bf16(kf, qf, z, 0, 0, 0);
        }
        bf16x8 vf[2][2];
        #pragma unroll
        for (int c = 0; c < 2; c++)
            #pragma unroll
            for (int hh = 0; hh < 2; hh++)
                vf[c][hh] = *(const bf16x8*)&Vt[cur][16 * hh + lr]
                                [((4 * c + lg) ^ (lr & 7)) * 8];

        float tm = s[0][0];
        #pragma unroll
        for (int t = 0; t < 4; t++)
            #pragma unroll
            for (int r = 0; r < 4; r++) tm = fmaxf(tm, s[t][r]);
        tm = fmaxf(tm, __shfl_xor(tm, 16));
        tm = fmaxf(tm, __shfl_xor(tm, 32));

        if (__any(tm > mrow)) {
            float mn = fmaxf(mrow, tm);
            float sc = __builtin_amdgcn_exp2f(mrow - mn);
            mrow = mn;
            lsum *= sc;
            #pragma unroll
            for (int r = 0; r < 4; r++) { acc0[r] *= sc; acc1[r] *= sc; }
        }

        float p[4][4];
        float rs = 0.0f;
        #pragma unroll
        for (int t = 0; t < 4; t++)
            #pragma unroll
            for (int r = 0; r < 4; r++) {
                p[t][r] = __builtin_amdgcn_exp2f(s[t][r] - mrow);
                rs += p[t][r];
            }
        rs += __shfl_xor(rs, 16);
        rs += __shfl_xor(rs, 32);
        lsum += rs;

        #pragma unroll
        for (int t = 0; t < 4; t++) {
            uint2 d;
            d.x = pk2(p[t][0], p[t][1]);
            d.y = pk2(p[t][2], p[t][3]);
            *(uint2*)&pbuf[w][lr][(16 * t + 4 * lg) ^ (lr & 8)] = d;
        }
        #pragma unroll
        for (int c = 0; c < 2; c++) {
            bf16x8 pf = *(const bf16x8*)&pbuf[w][lr][(32 * c + 8 * lg) ^ (lr & 8)];
            acc0 = __builtin_amdgcn_mfma_f32_16x16x32_bf16(vf[c][0], pf, acc0, 0, 0, 0);
            acc1 = __builtin_amdgcn_mfma_f32_16x16x32_bf16(vf[c][1], pf, acc1, 0, 0, 0);
        }

        // ---- stage tile t+1 into the other buffer ----
        if (it + 1 < N_ / KBLK_) {
            if (sh == 0) *(uint4*)&Kt[cur ^ 1][kkey][kslot * 8] = pr;
            else         *(uint4*)&Vt[cur ^ 1][vd][vphys]       = pr;
        }
        __syncthreads();
    }

    const float inv = 1.0f / lsum;
    uint2 o;
    o.x = pk2(acc0[0] * inv, acc0[1] * inv);
    o.y = pk2(acc0[2] * inv, acc0[3] * inv);
    *(uint2*)&AO[((size_t)b * N_ + q0 + lr) * C_ + h * HD_ + 4 * lg] = o;
    o.x = pk2(acc1[0] * inv, acc1[1] * inv);
    o.y = pk2(acc1[2] * inv, acc1[3] * inv);
    *(uint2*)&AO[((size_t)b * N_ + q0 + lr) * C_ + h * HD_ + 16 + 4 * lg] = o;
}

// ---------------------------------------------------------------------------
// proj_out: Out[b][d][n] = sum_c Wo[d][c] * AO[b][n][c] + bo[d]  (fp32 out)
//   grid (N/16, 1, B) = 512 blocks; wave = 64 do x 16 n.
// ---------------------------------------------------------------------------
__global__ __launch_bounds__(256) void proj_out(
    const short* __restrict__ AO, const float* __restrict__ W,
    const float* __restrict__ bias, float* __restrict__ Out)
{
    const int b = blockIdx.z;
    const int n0 = blockIdx.x * 16;
    const int tid = threadIdx.x, w = tid >> 6, l = tid & 63, lg = l >> 4, lr = l & 15;

    f32x4 acc[4] = {};

    for (int c0 = 0; c0 < C_; c0 += 32) {
        bf16x8 af[4];
        #pragma unroll
        for (int db = 0; db < 4; db++) {
            const float* wp = W + (size_t)(w * 64 + db * 16 + lr) * C_ + c0 + lg * 8;
            float t[8];
            *(float4*)t       = *(const float4*)wp;
            *(float4*)(t + 4) = *(const float4*)(wp + 4);
            #pragma unroll
            for (int i = 0; i < 8; i++) af[db][i] = f2b(t[i]);
        }
        bf16x8 bfr = *(const bf16x8*)&AO[((size_t)b * N_ + n0 + lr) * C_ + c0 + lg * 8];
        #pragma unroll
        for (int db = 0; db < 4; db++)
            acc[db] = __builtin_amdgcn_mfma_f32_16x16x32_bf16(af[db], bfr, acc[db], 0, 0, 0);
    }

    #pragma unroll
    for (int db = 0; db < 4; db++) {
        #pragma unroll
        for (int r = 0; r < 4; r++) {
            const int d = w * 64 + db * 16 + lg * 4 + r;
            Out[((size_t)(b * C_) + d) * N_ + n0 + lr] = acc[db][r] + bias[d];
        }
    }
}

// ---------------------------------------------------------------------------
extern "C" void kernel_launch(void* const* d_in, const int* in_sizes, int n_in,
                              void* d_out, int out_size, void* d_ws, size_t ws_size,
                              hipStream_t stream) {
    const float* dec = (const float*)d_in[0];
    const float* enc = (const float*)d_in[1];
    const float* Wq  = (const float*)d_in[2];
    const float* bq  = (const float*)d_in[3];
    const float* Wkv = (const float*)d_in[4];
    const float* bkv = (const float*)d_in[5];
    const float* Wo  = (const float*)d_in[6];
    const float* bo  = (const float*)d_in[7];
    float* out = (float*)d_out;

    const size_t SEG = (size_t)B_ * NH_ * N_ * HD_;  // 2,097,152 elements
    short* Qb  = (short*)d_ws;
    short* Kb  = Qb + SEG;
    short* Vb  = Kb + SEG;
    short* AOb = Vb + SEG;   // total 16 MB

    proj_qkv<<<dim3(N_ / 64, 6, B_), 256, 0, stream>>>(dec, enc, Wq, bq, Wkv, bkv,
                                                       Qb, Kb, Vb);
    attn_kernel<<<dim3(N_ / 128, NH_, B_), 512, 0, stream>>>(Qb, Kb, Vb, AOb);
    proj_out<<<dim3(N_ / 16, 1, B_), 256, 0, stream>>>(AOb, Wo, bo, out);
}

// Round 4
// 118.955 us; speedup vs baseline: 2.6188x; 1.1355x over previous
//
#include <hip/hip_runtime.h>
#include <hip/hip_bf16.h>

#define B_ 2
#define C_ 256
#define N_ 4096
#define NH_ 8
#define HD_ 32
#define KBLK_ 64
#define SCALE_ 0.17677669529663687f
#define LOG2E_ 1.4426950408889634f

typedef __attribute__((ext_vector_type(8))) short bf16x8;
typedef __attribute__((ext_vector_type(4))) float f32x4;

__device__ inline short f2b(float f) {
    __hip_bfloat16 h = __float2bfloat16(f);
    return __builtin_bit_cast(short, h);
}

__device__ inline unsigned pk2(float a, float b) {
    unsigned r;
    asm("v_cvt_pk_bf16_f32 %0, %1, %2" : "=v"(r) : "v"(a), "v"(b));
    return r;
}

// ---------------------------------------------------------------------------
// proj_qkv: fused Q/K/V projections, LDS-free (B-frags read as scalar dwords
// direct from In[c][n]; 4x64B coalesced segments per load instr; no barriers).
//   grid (N/64, 6, B): y<2 -> Q rows y*128; y=2,3 -> K rows; y=4,5 -> V rows.
//   Block = 128 do x 64 n, 4 waves (wave = 64 do x 32 n).
// ---------------------------------------------------------------------------
__global__ __launch_bounds__(256) void proj_qkv(
    const float* __restrict__ dec, const float* __restrict__ enc,
    const float* __restrict__ Wq, const float* __restrict__ bq,
    const float* __restrict__ Wkv, const float* __restrict__ bkv,
    short* __restrict__ Qb, short* __restrict__ Kb, short* __restrict__ Vb)
{
    const int b = blockIdx.z, y = blockIdx.y;
    const int n0 = blockIdx.x * 64;
    const bool isQ = (y < 2);
    const float* In   = isQ ? dec : enc;
    const float* W    = isQ ? Wq : Wkv;
    const float* bias = isQ ? bq : bkv;
    const int row0 = isQ ? y * 128 : (y - 2) * 128;

    const int tid = threadIdx.x;
    const int w = tid >> 6, l = tid & 63, lg = l >> 4, lr = l & 15;
    const int w2 = w >> 1, w1 = w & 1;   // do-half, n-half

    f32x4 acc[4][2] = {};
    const float* Inb = In + (size_t)b * C_ * N_;

    for (int c0 = 0; c0 < C_; c0 += 32) {
        bf16x8 af[4];
        #pragma unroll
        for (int db = 0; db < 4; db++) {
            const float* wp = W + (size_t)(row0 + w2 * 64 + db * 16 + lr) * C_ + c0 + lg * 8;
            float t[8];
            *(float4*)t       = *(const float4*)wp;
            *(float4*)(t + 4) = *(const float4*)(wp + 4);
            #pragma unroll
            for (int i = 0; i < 8; i++) af[db][i] = f2b(t[i]);
        }
        #pragma unroll
        for (int nb = 0; nb < 2; nb++) {
            const int n = n0 + w1 * 32 + nb * 16 + lr;
            bf16x8 bfr;
            #pragma unroll
            for (int j = 0; j < 8; j++)
                bfr[j] = f2b(Inb[(size_t)(c0 + 8 * lg + j) * N_ + n]);
            #pragma unroll
            for (int db = 0; db < 4; db++)
                acc[db][nb] = __builtin_amdgcn_mfma_f32_16x16x32_bf16(
                    af[db], bfr, acc[db][nb], 0, 0, 0);
        }
    }

    #pragma unroll
    for (int db = 0; db < 4; db++) {
        #pragma unroll
        for (int r = 0; r < 4; r++) {
            const int dl = row0 + w2 * 64 + db * 16 + lg * 4 + r;
            const float bs = bias[dl];
            #pragma unroll
            for (int nb = 0; nb < 2; nb++) {
                const int n = n0 + w1 * 32 + nb * 16 + lr;
                float v = acc[db][nb][r] + bs;
                if (y < 2) {
                    Qb[(((size_t)(b * NH_ + (dl >> 5)) * N_) + n) * HD_ + (dl & 31)]
                        = f2b(v * (SCALE_ * LOG2E_));
                } else if (y < 4) {
                    Kb[(((size_t)(b * NH_ + (dl >> 5)) * N_) + n) * HD_ + (dl & 31)]
                        = f2b(v);
                } else {
                    Vb[((size_t)(b * C_) + (dl - 256)) * N_ + n] = f2b(v);
                }
            }
        }
    }
}

// ---------------------------------------------------------------------------
// attn_kernel: flash attention, 8 waves x 16 q, KBLK=64, double-buffered LDS.
//   K staged with row-permutation pi(s)=32(t&1)+8lg+4(t>>1)+r so the QK^T
//   output registers ARE the PV B-fragment (P never touches LDS).
//   Kt slot-swizzled (slot^((row>>1)&3)); Vt slot-swizzled (slot^(d&7)).
//   Defer-max (THR=8, exp2 domain); lsum reduced cross-lane only at epilogue.
// ---------------------------------------------------------------------------
__global__ __launch_bounds__(512) void attn_kernel(
    const short* __restrict__ Qb, const short* __restrict__ Kb,
    const short* __restrict__ Vb, short* __restrict__ AO)
{
    const int lin = blockIdx.x + 32 * (blockIdx.y + 8 * blockIdx.z);
    const int wg  = (lin & 7) * 64 + (lin >> 3);
    const int qblk = wg & 31, h = (wg >> 5) & 7, b = wg >> 8;

    const int tid = threadIdx.x, w = tid >> 6, l = tid & 63;
    const int lg = l >> 4, lr = l & 15;
    const int q0 = qblk * 128 + w * 16;

    const short* Qp = Qb + ((size_t)(b * NH_ + h) * N_) * HD_;
    const short* Kp = Kb + ((size_t)(b * NH_ + h) * N_) * HD_;
    const short* Vp = Vb + ((size_t)(b * NH_ + h) * HD_) * N_;

    __shared__ short Kt[2][KBLK_][HD_];   // [slot-row][hd], 16B-slot ^ ((row>>1)&3)
    __shared__ short Vt[2][HD_][KBLK_];   // [d][key],      16B-slot ^ (d&7)

    // staging roles: threads 0-255 stage K, 256-511 stage V
    const int sh = tid >> 8;
    const int su = tid & 255;
    const int kkey = su >> 2, kslot = su & 3;
    const int kphys = (kslot ^ ((kkey >> 1) & 3)) * 8;
    // pi(s) = 32*((s>>4)&1) + 8*((s>>2)&3) + 4*((s>>5)&1) + (s&3)
    const int ksrc = ((kkey >> 4) & 1) * 32 + ((kkey >> 2) & 3) * 8
                   + ((kkey >> 5) & 1) * 4 + (kkey & 3);
    const int vd = su >> 3, vslot = su & 7;
    const int vphys = (vslot ^ (vd & 7)) * 8;

    const int krd = (lg ^ ((lr >> 1) & 3)) * 8;   // K-frag read slot (shorts)

    bf16x8 qf = *(const bf16x8*)&Qp[(size_t)(q0 + lr) * HD_ + lg * 8];

    f32x4 acc0 = {}, acc1 = {};     // out^T: d = 4lg+r (+16), q = lr
    float mrow = -1e30f, lsum = 0.0f;

    // prologue: stage tile 0
    {
        uint4 pr = (sh == 0)
            ? *(const uint4*)(Kp + (size_t)ksrc * HD_ + kslot * 8)
            : *(const uint4*)(Vp + (size_t)vd * N_ + vslot * 8);
        if (sh == 0) *(uint4*)&Kt[0][kkey][kphys] = pr;
        else         *(uint4*)&Vt[0][vd][vphys]   = pr;
    }
    __syncthreads();

    for (int it = 0; it < N_ / KBLK_; ++it) {
        const int cur = it & 1;
        const int mnext = (it + 1) * KBLK_;
        uint4 pr;
        if (it + 1 < N_ / KBLK_) {
            pr = (sh == 0)
                ? *(const uint4*)(Kp + (size_t)(mnext + ksrc) * HD_ + kslot * 8)
                : *(const uint4*)(Vp + (size_t)vd * N_ + mnext + vslot * 8);
        }

        // ---- QK^T: s[t][r] = score(q=lr, key = m0 + pi(16t+4lg+r)) ----
        f32x4 z = {};
        f32x4 s[4];
        __builtin_amdgcn_s_setprio(1);
        #pragma unroll
        for (int t = 0; t < 4; t++) {
            bf16x8 kf = *(const bf16x8*)&Kt[cur][16 * t + lr][krd];
            s[t] = __builtin_amdgcn_mfma_f32_16x16x32_bf16(kf, qf, z, 0, 0, 0);
        }
        __builtin_amdgcn_s_setprio(0);

        bf16x8 vf[2][2];
        #pragma unroll
        for (int c = 0; c < 2; c++)
            #pragma unroll
            for (int hh = 0; hh < 2; hh++)
                vf[c][hh] = *(const bf16x8*)&Vt[cur][16 * hh + lr]
                                [((4 * c + lg) ^ (lr & 7)) * 8];

        // ---- online softmax (defer-max, THR=8 in exp2 domain) ----
        float tm = s[0][0];
        #pragma unroll
        for (int t = 0; t < 4; t++)
            #pragma unroll
            for (int r = 0; r < 4; r++) tm = fmaxf(tm, s[t][r]);
        tm = fmaxf(tm, __shfl_xor(tm, 16));
        tm = fmaxf(tm, __shfl_xor(tm, 32));

        if (!__all(tm - mrow <= 8.0f)) {
            float mn = fmaxf(mrow, tm);
            float sc = __builtin_amdgcn_exp2f(mrow - mn);
            mrow = mn;
            lsum *= sc;
            #pragma unroll
            for (int r = 0; r < 4; r++) { acc0[r] *= sc; acc1[r] *= sc; }
        }

        float p[4][4];
        #pragma unroll
        for (int t = 0; t < 4; t++)
            #pragma unroll
            for (int r = 0; r < 4; r++) {
                p[t][r] = __builtin_amdgcn_exp2f(s[t][r] - mrow);
                lsum += p[t][r];
            }

        // ---- PV: P-frag assembled in registers (pi makes layout match) ----
        __builtin_amdgcn_s_setprio(1);
        #pragma unroll
        for (int c = 0; c < 2; c++) {
            union { bf16x8 v; unsigned u[4]; } pu;
            pu.u[0] = pk2(p[c][0], p[c][1]);
            pu.u[1] = pk2(p[c][2], p[c][3]);
            pu.u[2] = pk2(p[c + 2][0], p[c + 2][1]);
            pu.u[3] = pk2(p[c + 2][2], p[c + 2][3]);
            acc0 = __builtin_amdgcn_mfma_f32_16x16x32_bf16(vf[c][0], pu.v, acc0, 0, 0, 0);
            acc1 = __builtin_amdgcn_mfma_f32_16x16x32_bf16(vf[c][1], pu.v, acc1, 0, 0, 0);
        }
        __builtin_amdgcn_s_setprio(0);

        // ---- stage tile t+1 ----
        if (it + 1 < N_ / KBLK_) {
            if (sh == 0) *(uint4*)&Kt[cur ^ 1][kkey][kphys] = pr;
            else         *(uint4*)&Vt[cur ^ 1][vd][vphys]   = pr;
        }
        __syncthreads();
    }

    lsum += __shfl_xor(lsum, 16);
    lsum += __shfl_xor(lsum, 32);
    const float inv = 1.0f / lsum;
    uint2 o;
    o.x = pk2(acc0[0] * inv, acc0[1] * inv);
    o.y = pk2(acc0[2] * inv, acc0[3] * inv);
    *(uint2*)&AO[((size_t)b * N_ + q0 + lr) * C_ + h * HD_ + 4 * lg] = o;
    o.x = pk2(acc1[0] * inv, acc1[1] * inv);
    o.y = pk2(acc1[2] * inv, acc1[3] * inv);
    *(uint2*)&AO[((size_t)b * N_ + q0 + lr) * C_ + h * HD_ + 16 + 4 * lg] = o;
}

// ---------------------------------------------------------------------------
// proj_out: Out[b][d][n] = sum_c Wo[d][c] * AO[b][n][c] + bo[d]  (fp32 out)
//   grid (N/16, 1, B) = 512 blocks; wave = 64 do x 16 n. LDS-free.
// ---------------------------------------------------------------------------
__global__ __launch_bounds__(256) void proj_out(
    const short* __restrict__ AO, const float* __restrict__ W,
    const float* __restrict__ bias, float* __restrict__ Out)
{
    const int b = blockIdx.z;
    const int n0 = blockIdx.x * 16;
    const int tid = threadIdx.x, w = tid >> 6, l = tid & 63, lg = l >> 4, lr = l & 15;

    f32x4 acc[4] = {};

    for (int c0 = 0; c0 < C_; c0 += 32) {
        bf16x8 af[4];
        #pragma unroll
        for (int db = 0; db < 4; db++) {
            const float* wp = W + (size_t)(w * 64 + db * 16 + lr) * C_ + c0 + lg * 8;
            float t[8];
            *(float4*)t       = *(const float4*)wp;
            *(float4*)(t + 4) = *(const float4*)(wp + 4);
            #pragma unroll
            for (int i = 0; i < 8; i++) af[db][i] = f2b(t[i]);
        }
        bf16x8 bfr = *(const bf16x8*)&AO[((size_t)b * N_ + n0 + lr) * C_ + c0 + lg * 8];
        #pragma unroll
        for (int db = 0; db < 4; db++)
            acc[db] = __builtin_amdgcn_mfma_f32_16x16x32_bf16(af[db], bfr, acc[db], 0, 0, 0);
    }

    #pragma unroll
    for (int db = 0; db < 4; db++) {
        #pragma unroll
        for (int r = 0; r < 4; r++) {
            const int d = w * 64 + db * 16 + lg * 4 + r;
            Out[((size_t)(b * C_) + d) * N_ + n0 + lr] = acc[db][r] + bias[d];
        }
    }
}

// ---------------------------------------------------------------------------
extern "C" void kernel_launch(void* const* d_in, const int* in_sizes, int n_in,
                              void* d_out, int out_size, void* d_ws, size_t ws_size,
                              hipStream_t stream) {
    const float* dec = (const float*)d_in[0];
    const float* enc = (const float*)d_in[1];
    const float* Wq  = (const float*)d_in[2];
    const float* bq  = (const float*)d_in[3];
    const float* Wkv = (const float*)d_in[4];
    const float* bkv = (const float*)d_in[5];
    const float* Wo  = (const float*)d_in[6];
    const float* bo  = (const float*)d_in[7];
    float* out = (float*)d_out;

    const size_t SEG = (size_t)B_ * NH_ * N_ * HD_;  // 2,097,152 elements
    short* Qb  = (short*)d_ws;
    short* Kb  = Qb + SEG;
    short* Vb  = Kb + SEG;
    short* AOb = Vb + SEG;   // total 16 MB

    proj_qkv<<<dim3(N_ / 64, 6, B_), 256, 0, stream>>>(dec, enc, Wq, bq, Wkv, bkv,
                                                       Qb, Kb, Vb);
    attn_kernel<<<dim3(N_ / 128, NH_, B_), 512, 0, stream>>>(Qb, Kb, Vb, AOb);
    proj_out<<<dim3(N_ / 16, 1, B_), 256, 0, stream>>>(AOb, Wo, bo, out);
}